// Round 2
// baseline (141.893 us; speedup 1.0000x reference)
//
#include <hip/hip_runtime.h>

// SSIM (window=3, stride=3, pad=1) on (16,3,512,512) fp32 -> scalar mean.
// V11 = V9 compute/config (proven best, 119.4us, absmax 0.0) + FUSED FINAL
// REDUCTION (last-block-done pattern), eliminating the 2nd kernel + its gap.
// R1 post-mortem: depth-2 pipeline (V10) was neutral (+1.6%): with full
// unroll LLVM already hoists loads arbitrarily early, so source-level depth
// only raised VGPR pressure; and bounds(256,2) made block 513 run a 2nd
// generation. Reverted both. Little's law says main is already near its
// 16us BW floor (in-flight/CU ~50-100KB >> 9.2KB needed at 900cyc latency),
// so the only controllable slices left are the ssim_final dispatch (~4us)
// and its inter-kernel gap. Fuse: memset 16B of ws -> {f64 sum, u32 ticket};
// each block atomicAdd(f64 partial) -> fence -> ticket; last block (ticket
// == NBLK-1) does coherent read (atomicAdd(p,0.0) -- plain load may be
// stale cross-XCD) and writes out[0]. f64 accumulation: error ~1e-9.
// Fixed floor context: 2x41us harness poison fills + ~16us BW floor.

#define HW       512
#define PLANE_SZ (HW * HW)
#define OHW      171                    // (512 + 2 - 3)/3 + 1
#define NPLANE   48                     // 16 batch * 3 channels
#define NOUT     (NPLANE * OHW * OHW)   // 1,403,568
#define NTASK    (NPLANE * OHW)         // 8208 row-tasks
#define TPW      4                      // tasks per wave (8208 = 2052*4)
#define NWAVE    (NTASK / TPW)          // 2052
#define TPB      256
#define WPB      4
#define NBLK     (NWAVE / WPB)          // 513 (exact)

typedef float f4 __attribute__((ext_vector_type(4)));

struct TD { f4 xa[3][2]; f4 xb[3][2]; };   // one row-task's data (12 f4)

__device__ __forceinline__ float ssim_val(float s1, float s2, float s11,
                                          float s22, float s12) {
  const float C1 = 1e-4f, C2 = 9e-4f;
  const float m11 = s1 * s1, m22 = s2 * s2, m12 = s1 * s2;
  const float sg1 = s11 - m11, sg2 = s22 - m22, sg12 = s12 - m12;
  const float num = (2.0f * m12 + C1) * (2.0f * sg12 + C2);
  const float den = (m11 + m22 + C1) * (sg1 + sg2 + C2);
  return num * __builtin_amdgcn_rcpf(den);   // rel err ~1e-7 << 2.4e-4 thr
}

__device__ __forceinline__ void load_task(const float* __restrict__ img1,
                                          const float* __restrict__ img2,
                                          int task, int lane, TD& d) {
  const int plane = task / OHW;
  const int oy    = task - plane * OHW;
  const int r0    = 3 * oy - 1;
  const int rr0   = (r0 < 0) ? 0 : r0;
  const float* a = img1 + (size_t)plane * PLANE_SZ;
  const float* b = img2 + (size_t)plane * PLANE_SZ;
#pragma unroll
  for (int k = 0; k < 3; ++k) {
    const int r = (k == 0) ? rr0 : (r0 + k);
    const f4* ra = (const f4*)(a + (size_t)r * HW);
    const f4* rb = (const f4*)(b + (size_t)r * HW);
    d.xa[k][0] = ra[lane];      d.xa[k][1] = ra[lane + 64];
    d.xb[k][0] = rb[lane];      d.xb[k][1] = rb[lane + 64];
  }
}

__device__ __forceinline__ float task_ssim(const TD& d, int oy, int lane,
                                           float wy0, float wy1, float wy2,
                                           float wx0, float wx1, float wx2) {
  float wyv[3];
  wyv[0] = (oy == 0) ? 0.0f : wy0;             // top pad: zero-weight row 0
  wyv[1] = wy1;
  wyv[2] = wy2;

  float acc = 0.0f;
  float fwd[5];
#pragma unroll
  for (int c = 0; c < 2; ++c) {
    // chunk start col c0 = 256*c + 4*lane; m = c0 % 3 (256 % 3 == 1)
    const int m = (lane + c) % 3;

    float P1[4]  = {0.f, 0.f, 0.f, 0.f};
    float P2[4]  = {0.f, 0.f, 0.f, 0.f};
    float P11[4] = {0.f, 0.f, 0.f, 0.f};
    float P22[4] = {0.f, 0.f, 0.f, 0.f};
    float P12[4] = {0.f, 0.f, 0.f, 0.f};
#pragma unroll
    for (int k = 0; k < 3; ++k) {
      const float wyk = wyv[k];
#pragma unroll
      for (int j = 0; j < 4; ++j) {
        const float x = d.xa[k][c][j];
        const float y = d.xb[k][c][j];
        const float u = wyk * x;
        const float v = wyk * y;
        P1[j] += u;
        P2[j] += v;
        P11[j] = fmaf(u, x, P11[j]);
        P22[j] = fmaf(v, y, P22[j]);
        P12[j] = fmaf(u, y, P12[j]);
      }
    }

    float wxl[4];
#pragma unroll
    for (int j = 0; j < 4; ++j) {
      const int ix = (m + j + 1) % 3;
      wxl[j] = (ix == 0) ? wx0 : ((ix == 1) ? wx1 : wx2);
    }

    const float aL = (m != 1) ? 1.0f : 0.0f;
    const float bL = (m == 2) ? 1.0f : 0.0f;
    float L[5], R[5];
    {
      float t0, t1, t2, t3, full, left;
#define BIN(Q, P)                                              \
      t0 = wxl[0] * P[0]; t1 = wxl[1] * P[1];                  \
      t2 = wxl[2] * P[2]; t3 = wxl[3] * P[3];                  \
      full = (t0 + t1) + (t2 + t3);                            \
      left = fmaf(bL, t2, fmaf(aL, t1, t0));                   \
      L[Q] = left; R[Q] = full - left;
      BIN(0, P1) BIN(1, P2) BIN(2, P11) BIN(3, P22) BIN(4, P12)
#undef BIN
    }
    if (c == 0) {
#pragma unroll
      for (int q = 0; q < 5; ++q) fwd[q] = R[q];
    }

    const float allow =
        (m != 2 && !(c == 0 && lane == 0)) ? 1.0f : 0.0f;  // lane0 A: left pad
#pragma unroll
    for (int q = 0; q < 5; ++q) {
      float up = __shfl_up(R[q], 1, 64);
      if (c == 1) {
        const float seam = __shfl(fwd[q], 63, 64);  // chunk-A lane63 R
        up = (lane == 0) ? seam : up;
      }
      L[q] = fmaf(allow, up, L[q]);
    }

    const float mR = (m == 1) ? 1.0f : 0.0f;
    acc += ssim_val(L[0], L[1], L[2], L[3], L[4]);
    acc += mR * ssim_val(R[0], R[1], R[2], R[3], R[4]);
  }
  return acc;
}

__global__ __launch_bounds__(TPB, 3) void ssim_main(
    const float* __restrict__ img1, const float* __restrict__ img2,
    const float* __restrict__ win, double* __restrict__ wsacc,
    float* __restrict__ out) {
  const int lane = threadIdx.x & 63;
  const int wv   = threadIdx.x >> 6;
  const int wave = blockIdx.x * WPB + wv;      // 0..2051 (grid exact)
  const int base = wave * TPW;                 // 4 consecutive row-tasks

  // Separable window: w[3r+c] = wy[r]*wx[c] (window = outer(g,g)).
  float wy[3], wx[3];
#pragma unroll
  for (int k = 0; k < 3; ++k) {
    wy[k] = win[3 * k] + win[3 * k + 1] + win[3 * k + 2];
    wx[k] = win[k] + win[k + 3] + win[k + 6];
  }

  TD cur, nxt;
  load_task(img1, img2, base, lane, cur);      // prologue loads

  float acc = 0.0f;
#pragma unroll
  for (int t = 0; t < TPW; ++t) {
    if (t + 1 < TPW)
      load_task(img1, img2, base + t + 1, lane, nxt);  // issue BEFORE consume
    const int task  = base + t;
    const int plane = task / OHW;
    const int oy    = task - plane * OHW;
    acc += task_ssim(cur, oy, lane, wy[0], wy[1], wy[2], wx[0], wx[1], wx[2]);
    if (t + 1 < TPW) cur = nxt;                // SSA rename after full unroll
  }

  // wave(64) shuffle reduce -> LDS -> one f64 atomic per block (fused final)
#pragma unroll
  for (int off = 32; off > 0; off >>= 1) acc += __shfl_down(acc, off, 64);
  __shared__ float wsum[TPB / 64];
  if (lane == 0) wsum[wv] = acc;
  __syncthreads();
  if (threadIdx.x == 0) {
    float s = 0.f;
#pragma unroll
    for (int i = 0; i < TPB / 64; ++i) s += wsum[i];
    // ws layout (memset to 0 each iteration): [0..7] f64 sum, [8..11] ticket
    double* dsum = wsacc;
    unsigned* ticket = (unsigned*)(wsacc + 1);
    atomicAdd(dsum, (double)s);                // device-scope RMW
    __threadfence();                           // release: sum before ticket
    const unsigned old = atomicAdd(ticket, 1u);
    if (old == NBLK - 1) {                     // last block to arrive
      __threadfence();                         // acquire
      const double total = atomicAdd(dsum, 0.0);  // coherent read (cross-XCD)
      out[0] = (float)(total / (double)NOUT);
    }
  }
}

extern "C" void kernel_launch(void* const* d_in, const int* in_sizes, int n_in,
                              void* d_out, int out_size, void* d_ws, size_t ws_size,
                              hipStream_t stream) {
  const float* img1 = (const float*)d_in[0];
  const float* img2 = (const float*)d_in[1];
  const float* win  = (const float*)d_in[2];
  float* out = (float*)d_out;

  // Zero the 16-byte accumulator block {f64 sum, u32 ticket, pad} each
  // iteration. hipMemsetAsync is graph-capturable (harness's own poison
  // fills are memsets); forbidden list is malloc/free/memcpy(sync)/events.
  hipMemsetAsync(d_ws, 0, 16, stream);
  ssim_main<<<NBLK, TPB, 0, stream>>>(img1, img2, win, (double*)d_ws, out);
}

// Round 3
// 119.329 us; speedup vs baseline: 1.1891x; 1.1891x over previous
//
#include <hip/hip_runtime.h>

// SSIM (window=3, stride=3, pad=1) on (16,3,512,512) fp32 -> scalar mean.
// V12 = V9 compute + two-kernel ending (proven, absmax 0.0), ONE change:
// TPW 4 -> 2 (waves 2052 -> 4104) to double TLP.
// R2 post-mortem: fused atomic tail (V11) cost ~20us -- 1026 contended
// same-line device atomics serialize cross-XCD; REVERTED to two kernels.
// R2's counters (first real look at main): FETCH=50MB (L3 serves half the
// 100.7MB input -> BW floor ~10-12us), VALUBusy 9.5%, Occupancy 12%,
// main ~30us (back-inferred for V9) = 2.5-3x over floor with both pipes
// idle => latency-bound, TLP-starved (grid supplies only 8 waves/CU).
// Unlike V10 (ILP depth the compiler already had), the compiler cannot
// create waves: TPW=2 doubles independent 12KB load bursts per CU.
// Fixed floor context: 2x41us harness poison fills + ~7us final/gaps.

#define HW       512
#define PLANE_SZ (HW * HW)
#define OHW      171                    // (512 + 2 - 3)/3 + 1
#define NPLANE   48                     // 16 batch * 3 channels
#define NOUT     (NPLANE * OHW * OHW)   // 1,403,568
#define NTASK    (NPLANE * OHW)         // 8208 row-tasks
#define TPW      2                      // tasks per wave (8208 = 4104*2)
#define NWAVE    (NTASK / TPW)          // 4104
#define TPB      256
#define WPB      4
#define NBLK     (NWAVE / WPB)          // 1026 (exact)

typedef float f4 __attribute__((ext_vector_type(4)));

struct TD { f4 xa[3][2]; f4 xb[3][2]; };   // one row-task's data (12 f4)

__device__ __forceinline__ float ssim_val(float s1, float s2, float s11,
                                          float s22, float s12) {
  const float C1 = 1e-4f, C2 = 9e-4f;
  const float m11 = s1 * s1, m22 = s2 * s2, m12 = s1 * s2;
  const float sg1 = s11 - m11, sg2 = s22 - m22, sg12 = s12 - m12;
  const float num = (2.0f * m12 + C1) * (2.0f * sg12 + C2);
  const float den = (m11 + m22 + C1) * (sg1 + sg2 + C2);
  return num * __builtin_amdgcn_rcpf(den);   // rel err ~1e-7 << 2.4e-4 thr
}

__device__ __forceinline__ void load_task(const float* __restrict__ img1,
                                          const float* __restrict__ img2,
                                          int task, int lane, TD& d) {
  const int plane = task / OHW;
  const int oy    = task - plane * OHW;
  const int r0    = 3 * oy - 1;
  const int rr0   = (r0 < 0) ? 0 : r0;
  const float* a = img1 + (size_t)plane * PLANE_SZ;
  const float* b = img2 + (size_t)plane * PLANE_SZ;
#pragma unroll
  for (int k = 0; k < 3; ++k) {
    const int r = (k == 0) ? rr0 : (r0 + k);
    const f4* ra = (const f4*)(a + (size_t)r * HW);
    const f4* rb = (const f4*)(b + (size_t)r * HW);
    d.xa[k][0] = ra[lane];      d.xa[k][1] = ra[lane + 64];
    d.xb[k][0] = rb[lane];      d.xb[k][1] = rb[lane + 64];
  }
}

__device__ __forceinline__ float task_ssim(const TD& d, int oy, int lane,
                                           float wy0, float wy1, float wy2,
                                           float wx0, float wx1, float wx2) {
  float wyv[3];
  wyv[0] = (oy == 0) ? 0.0f : wy0;             // top pad: zero-weight row 0
  wyv[1] = wy1;
  wyv[2] = wy2;

  float acc = 0.0f;
  float fwd[5];
#pragma unroll
  for (int c = 0; c < 2; ++c) {
    // chunk start col c0 = 256*c + 4*lane; m = c0 % 3 (256 % 3 == 1)
    const int m = (lane + c) % 3;

    float P1[4]  = {0.f, 0.f, 0.f, 0.f};
    float P2[4]  = {0.f, 0.f, 0.f, 0.f};
    float P11[4] = {0.f, 0.f, 0.f, 0.f};
    float P22[4] = {0.f, 0.f, 0.f, 0.f};
    float P12[4] = {0.f, 0.f, 0.f, 0.f};
#pragma unroll
    for (int k = 0; k < 3; ++k) {
      const float wyk = wyv[k];
#pragma unroll
      for (int j = 0; j < 4; ++j) {
        const float x = d.xa[k][c][j];
        const float y = d.xb[k][c][j];
        const float u = wyk * x;
        const float v = wyk * y;
        P1[j] += u;
        P2[j] += v;
        P11[j] = fmaf(u, x, P11[j]);
        P22[j] = fmaf(v, y, P22[j]);
        P12[j] = fmaf(u, y, P12[j]);
      }
    }

    float wxl[4];
#pragma unroll
    for (int j = 0; j < 4; ++j) {
      const int ix = (m + j + 1) % 3;
      wxl[j] = (ix == 0) ? wx0 : ((ix == 1) ? wx1 : wx2);
    }

    const float aL = (m != 1) ? 1.0f : 0.0f;
    const float bL = (m == 2) ? 1.0f : 0.0f;
    float L[5], R[5];
    {
      float t0, t1, t2, t3, full, left;
#define BIN(Q, P)                                              \
      t0 = wxl[0] * P[0]; t1 = wxl[1] * P[1];                  \
      t2 = wxl[2] * P[2]; t3 = wxl[3] * P[3];                  \
      full = (t0 + t1) + (t2 + t3);                            \
      left = fmaf(bL, t2, fmaf(aL, t1, t0));                   \
      L[Q] = left; R[Q] = full - left;
      BIN(0, P1) BIN(1, P2) BIN(2, P11) BIN(3, P22) BIN(4, P12)
#undef BIN
    }
    if (c == 0) {
#pragma unroll
      for (int q = 0; q < 5; ++q) fwd[q] = R[q];
    }

    const float allow =
        (m != 2 && !(c == 0 && lane == 0)) ? 1.0f : 0.0f;  // lane0 A: left pad
#pragma unroll
    for (int q = 0; q < 5; ++q) {
      float up = __shfl_up(R[q], 1, 64);
      if (c == 1) {
        const float seam = __shfl(fwd[q], 63, 64);  // chunk-A lane63 R
        up = (lane == 0) ? seam : up;
      }
      L[q] = fmaf(allow, up, L[q]);
    }

    const float mR = (m == 1) ? 1.0f : 0.0f;
    acc += ssim_val(L[0], L[1], L[2], L[3], L[4]);
    acc += mR * ssim_val(R[0], R[1], R[2], R[3], R[4]);
  }
  return acc;
}

__global__ __launch_bounds__(TPB, 3) void ssim_main(
    const float* __restrict__ img1, const float* __restrict__ img2,
    const float* __restrict__ win, float* __restrict__ partial) {
  const int lane = threadIdx.x & 63;
  const int wv   = threadIdx.x >> 6;
  const int wave = blockIdx.x * WPB + wv;      // 0..4103 (grid exact)
  const int base = wave * TPW;                 // 2 consecutive row-tasks

  // Separable window: w[3r+c] = wy[r]*wx[c] (window = outer(g,g)).
  float wy[3], wx[3];
#pragma unroll
  for (int k = 0; k < 3; ++k) {
    wy[k] = win[3 * k] + win[3 * k + 1] + win[3 * k + 2];
    wx[k] = win[k] + win[k + 3] + win[k + 6];
  }

  TD cur, nxt;
  load_task(img1, img2, base, lane, cur);      // prologue loads

  float acc = 0.0f;
#pragma unroll
  for (int t = 0; t < TPW; ++t) {
    if (t + 1 < TPW)
      load_task(img1, img2, base + t + 1, lane, nxt);  // issue BEFORE consume
    const int task  = base + t;
    const int plane = task / OHW;
    const int oy    = task - plane * OHW;
    acc += task_ssim(cur, oy, lane, wy[0], wy[1], wy[2], wx[0], wx[1], wx[2]);
    if (t + 1 < TPW) cur = nxt;                // SSA rename after full unroll
  }

  // wave(64) shuffle reduce -> LDS -> one write per block (proven pattern)
#pragma unroll
  for (int off = 32; off > 0; off >>= 1) acc += __shfl_down(acc, off, 64);
  __shared__ float wsum[TPB / 64];
  if (lane == 0) wsum[wv] = acc;
  __syncthreads();
  if (threadIdx.x == 0) {
    float s = 0.f;
#pragma unroll
    for (int i = 0; i < TPB / 64; ++i) s += wsum[i];
    partial[blockIdx.x] = s;   // every block writes its slot: no init needed
  }
}

__global__ __launch_bounds__(256) void ssim_final(
    const float* __restrict__ partial, float* __restrict__ out) {
  double acc = 0.0;
  for (int i = threadIdx.x; i < NBLK; i += 256) acc += (double)partial[i];
#pragma unroll
  for (int off = 32; off > 0; off >>= 1) acc += __shfl_down(acc, off, 64);
  __shared__ double wsum[4];
  const int lane = threadIdx.x & 63, wid = threadIdx.x >> 6;
  if (lane == 0) wsum[wid] = acc;
  __syncthreads();
  if (threadIdx.x == 0) {
    double s = 0.0;
#pragma unroll
    for (int i = 0; i < 4; ++i) s += wsum[i];
    out[0] = (float)(s / (double)NOUT);
  }
}

extern "C" void kernel_launch(void* const* d_in, const int* in_sizes, int n_in,
                              void* d_out, int out_size, void* d_ws, size_t ws_size,
                              hipStream_t stream) {
  const float* img1 = (const float*)d_in[0];
  const float* img2 = (const float*)d_in[1];
  const float* win  = (const float*)d_in[2];
  float* partial = (float*)d_ws;   // NBLK floats
  float* out = (float*)d_out;

  ssim_main<<<NBLK, TPB, 0, stream>>>(img1, img2, win, partial);
  ssim_final<<<1, 256, 0, stream>>>(partial, out);
}